// Round 3
// baseline (446.091 us; speedup 1.0000x reference)
//
#include <hip/hip_runtime.h>
#include <hip/hip_bf16.h>

// Gaussian-splat heatmap, banded two-phase, FLOAT32 output.
//   x_t [B=512, T=64, 2] f32 in [0,100) -> heat [B, 200, 200] max-normalized.
// d_out is float32 per the reference's output dtype (jnp.float32); previous
// rounds wrote packed bf16 which under this hypothesis produced the saturated
// absmax=1.0 signature (half the f32 buffer junk-in-[0,1], half zeros).
// One block per image; 4 bands of 50 rows (band accumulator 40,000 B in LDS).
// Phase 1: splat each band, track running max. Phase 2: re-splat, write f32.

#define HH 200
#define WW 200
#define HALF 18          // kernel half-size (SIZE=36)
#define KSZ 37
#define NT 64            // points per image
#define BLK 256
#define BANDS 4
#define BROWS 50         // HH / BANDS
#define BPIX (BROWS * WW)   // 10000

__global__ __launch_bounds__(BLK) void heatmap_kernel(const float* __restrict__ x_t,
                                                      float* __restrict__ out) {
    __shared__ __align__(16) float bheat[BPIX];   // 40,000 B band accumulator
    __shared__ float k1n[KSZ];                    // normalized 1-D gaussian
    __shared__ unsigned int meta[NT];             // xs | ys<<8 | kx<<16 | ky<<24
    __shared__ float wmax[BLK / 64];

    const int tid = threadIdx.x;
    const int b = blockIdx.x;

    // --- normalized 1-D kernel: k1n[i] = exp(-(i-18)^2/18)/sum; kern[r][c]=k1n[r]*k1n[c] ---
    if (tid < KSZ) {
        float s = 0.0f, mine = 0.0f;
        #pragma unroll
        for (int i = 0; i < KSZ; ++i) {
            float r = (float)(i - HALF);
            float v = expf(-(r * r) * (1.0f / 18.0f));   // sigma=3 -> 2*sigma^2 = 18
            s += v;
            if (i == tid) mine = v;
        }
        k1n[tid] = mine / s;
    }

    // --- per-point metadata (replicates reference exactly) ---
    if (tid < NT) {
        float x = x_t[((size_t)b * NT + tid) * 2 + 0];
        float y = x_t[((size_t)b * NT + tid) * 2 + 1];
        bool valid = (x == x) && (y == y);            // !isnan
        int xp = (int)(x * 2.0f);                     // trunc toward 0 == astype(int32) for x>=0
        int yp = HH - (int)(y * 2.0f);
        int xs = min(max(xp - HALF, 0), WW - 2 * HALF);   // clip(.., 0, 164)
        int ys = min(max(yp - HALF, 0), HH - 2 * HALF);
        int xe = min(max(xp + HALF, 0), WW);
        int ye = min(max(yp + HALF, 0), HH);
        int kx = valid ? (xe - xs) : 0;               // <= 36: kernel row/col 36 never used
        int ky = valid ? (ye - ys) : 0;
        meta[tid] = (unsigned)xs | ((unsigned)ys << 8) |
                    ((unsigned)kx << 16) | ((unsigned)ky << 24);
    }

    float gmax = 0.0f;

    // ---- phase 1: per-band splat, accumulate max in registers ----
    for (int band = 0; band < BANDS; ++band) {
        const int row0 = band * BROWS;
        __syncthreads();                               // meta/k1n ready; prior scan done
        for (int i = tid; i < BPIX; i += BLK) bheat[i] = 0.0f;
        __syncthreads();
        // jobs = (point, kernel-row); splat rows that intersect this band
        for (int j = tid; j < NT * 36; j += BLK) {
            int p = j / 36;
            int r = j - p * 36;
            unsigned mw = meta[p];
            if (r < (int)(mw >> 24)) {                 // r < ky
                int row = (int)((mw >> 8) & 0xFF) + r; // ys + r
                if (row >= row0 && row < row0 + BROWS) {
                    int xs = (int)(mw & 0xFF);
                    int kx = (int)((mw >> 16) & 0xFF);
                    float wr = k1n[r];
                    float* dst = &bheat[(row - row0) * WW + xs];
                    for (int c = 0; c < kx; ++c)
                        atomicAdd(&dst[c], wr * k1n[c]);
                }
            }
        }
        __syncthreads();
        for (int i = tid; i < BPIX; i += BLK) gmax = fmaxf(gmax, bheat[i]);
    }

    // ---- block max reduce (heat >= 0, so 0-init is safe) ----
    #pragma unroll
    for (int off = 32; off > 0; off >>= 1) gmax = fmaxf(gmax, __shfl_xor(gmax, off));
    __syncthreads();
    if ((tid & 63) == 0) wmax[tid >> 6] = gmax;
    __syncthreads();
    float mm = fmaxf(fmaxf(wmax[0], wmax[1]), fmaxf(wmax[2], wmax[3]));
    const float scale = 1.0f / (mm + 1e-10f);

    // ---- phase 2: re-splat each band, write normalized float32 ----
    for (int band = 0; band < BANDS; ++band) {
        const int row0 = band * BROWS;
        __syncthreads();                               // prior band writeout done
        for (int i = tid; i < BPIX; i += BLK) bheat[i] = 0.0f;
        __syncthreads();
        for (int j = tid; j < NT * 36; j += BLK) {
            int p = j / 36;
            int r = j - p * 36;
            unsigned mw = meta[p];
            if (r < (int)(mw >> 24)) {
                int row = (int)((mw >> 8) & 0xFF) + r;
                if (row >= row0 && row < row0 + BROWS) {
                    int xs = (int)(mw & 0xFF);
                    int kx = (int)((mw >> 16) & 0xFF);
                    float wr = k1n[r];
                    float* dst = &bheat[(row - row0) * WW + xs];
                    for (int c = 0; c < kx; ++c)
                        atomicAdd(&dst[c], wr * k1n[c]);
                }
            }
        }
        __syncthreads();
        float* ob = out + (size_t)b * (HH * WW) + (size_t)row0 * WW;
        for (int i = tid; i < BPIX / 4; i += BLK) {
            float4 v = ((const float4*)bheat)[i];
            v.x *= scale; v.y *= scale; v.z *= scale; v.w *= scale;
            ((float4*)ob)[i] = v;
        }
    }
}

extern "C" void kernel_launch(void* const* d_in, const int* in_sizes, int n_in,
                              void* d_out, int out_size, void* d_ws, size_t ws_size,
                              hipStream_t stream) {
    const float* x_t = (const float*)d_in[0];
    float* out = (float*)d_out;
    const int B = in_sizes[0] / (NT * 2);   // 512
    heatmap_kernel<<<B, BLK, 0, stream>>>(x_t, out);
}

// Round 4
// 183.194 us; speedup vs baseline: 2.4351x; 2.4351x over previous
//
#include <hip/hip_runtime.h>

// Gaussian-splat heatmap via separable GATHER (no atomics).
//   x_t [B=512, T=64, 2] f32 -> heat [B, 200, 200] f32, per-image max-normalized.
// kern[r][c] = k1n[r]*k1n[c], so heat[y][x] = sum_p k1n[y-ys_p] * Cmat[p][x],
// Cmat[p][x] = k1n[x-xs_p] if 0<=x-xs_p<kx_p else 0 (reference's top-left-slice quirk).
// One block per image: build Cmat[64][200] in LDS + per-row 64-bit active-point
// bitmasks; each wave computes 50 rows, each lane 4 columns via one ds_read_b128
// per active point. Pass 1 finds the max, pass 2 recomputes and writes normalized.

#define HH 200
#define WW 200
#define HALF 18          // kernel half-size (SIZE=36)
#define KSZ 37
#define NT 64            // points per image
#define BLK 256
#define RPW 50           // rows per wave (4 waves * 50 = 200)

struct SMem {
    float Cmat[NT][WW];          // 51,200 B; row stride 800 B (16B-aligned)
    float k1n[KSZ];              // normalized 1-D gaussian
    unsigned meta[NT];           // xs | ys<<8 | kx<<16 | ky<<24
    unsigned rowmask[HH][2];     // per-row active-point bitmask (2x32)
    float wmax[4];
};

static __device__ inline void mask_accum(const SMem& s, unsigned m, int pbase,
                                         int y, int xb, float4& acc) {
    while (m) {
        int p = pbase + (__builtin_ctz(m));
        m &= m - 1;
        unsigned mw = s.meta[p];
        float R = s.k1n[y - (int)((mw >> 8) & 0xFF)];     // y-ys in [0, ky) subset [0,36]
        const float4 C = *(const float4*)&s.Cmat[p][xb];
        acc.x = fmaf(R, C.x, acc.x);
        acc.y = fmaf(R, C.y, acc.y);
        acc.z = fmaf(R, C.z, acc.z);
        acc.w = fmaf(R, C.w, acc.w);
    }
}

static __device__ inline float4 row_acc(const SMem& s, int y, int xb) {
    float4 acc = {0.0f, 0.0f, 0.0f, 0.0f};
    mask_accum(s, s.rowmask[y][0], 0, y, xb, acc);
    mask_accum(s, s.rowmask[y][1], 32, y, xb, acc);
    return acc;
}

__global__ __launch_bounds__(BLK) void heatmap_kernel(const float* __restrict__ x_t,
                                                      float* __restrict__ out) {
    __shared__ SMem s;
    const int tid  = threadIdx.x;
    const int lane = tid & 63;
    const int wv   = tid >> 6;
    const int b    = blockIdx.x;

    // --- phase A: zero rowmask; normalized 1-D kernel ---
    for (int i = tid; i < HH * 2; i += BLK) (&s.rowmask[0][0])[i] = 0u;
    if (tid < KSZ) {
        float sum = 0.0f, mine = 0.0f;
        #pragma unroll
        for (int i = 0; i < KSZ; ++i) {
            float r = (float)(i - HALF);
            float v = expf(-(r * r) * (1.0f / 18.0f));    // sigma=3 -> 2*sigma^2=18
            sum += v;
            if (i == tid) mine = v;
        }
        s.k1n[tid] = mine / sum;
    }
    __syncthreads();

    // --- phase B: per-point meta (replicates reference exactly) + rowmask bits ---
    if (tid < NT) {
        float x = x_t[((size_t)b * NT + tid) * 2 + 0];
        float y = x_t[((size_t)b * NT + tid) * 2 + 1];
        bool valid = (x == x) && (y == y);                // !isnan
        int xp = (int)(x * 2.0f);                         // trunc == astype(int32), x>=0
        int yp = HH - (int)(y * 2.0f);
        int xs = min(max(xp - HALF, 0), WW - 2 * HALF);   // clip(.., 0, 164)
        int ys = min(max(yp - HALF, 0), HH - 2 * HALF);
        int xe = min(max(xp + HALF, 0), WW);
        int ye = min(max(yp + HALF, 0), HH);
        int kx = valid ? (xe - xs) : 0;                   // <= 36 always
        int ky = valid ? (ye - ys) : 0;
        s.meta[tid] = (unsigned)xs | ((unsigned)ys << 8) |
                      ((unsigned)kx << 16) | ((unsigned)ky << 24);
        unsigned bit = 1u << (tid & 31);
        for (int r = 0; r < ky; ++r)
            atomicOr(&s.rowmask[ys + r][tid >> 5], bit);
    }
    __syncthreads();

    // --- phase C: build Cmat; 4 threads per point, 50 consecutive cols each ---
    {
        int p  = tid >> 2;
        unsigned mw = s.meta[p];
        int xs = (int)(mw & 0xFF);
        unsigned kx = (mw >> 16) & 0xFF;
        int x0 = (tid & 3) * 50;
        #pragma unroll 10
        for (int k = 0; k < 50; ++k) {
            int x = x0 + k;
            unsigned c = (unsigned)(x - xs);
            s.Cmat[p][x] = (c < kx) ? s.k1n[c] : 0.0f;
        }
    }
    __syncthreads();

    const int y0 = wv * RPW;
    const int xb = min(lane * 4, WW - 4);   // lanes >=50 duplicate cols 196..199 (benign)

    // --- pass 1: compute rows, track max (heat >= 0; duplicates can't exceed max) ---
    float m = 0.0f;
    for (int y = y0; y < y0 + RPW; ++y) {
        float4 a = row_acc(s, y, xb);
        m = fmaxf(m, fmaxf(fmaxf(a.x, a.y), fmaxf(a.z, a.w)));
    }
    #pragma unroll
    for (int off = 32; off > 0; off >>= 1) m = fmaxf(m, __shfl_xor(m, off));
    if (lane == 0) s.wmax[wv] = m;
    __syncthreads();
    const float mm = fmaxf(fmaxf(s.wmax[0], s.wmax[1]), fmaxf(s.wmax[2], s.wmax[3]));
    const float scale = 1.0f / (mm + 1e-10f);

    // --- pass 2: recompute, normalize, coalesced float4 store ---
    float* ob = out + (size_t)b * (HH * WW);
    for (int y = y0; y < y0 + RPW; ++y) {
        float4 a = row_acc(s, y, xb);
        a.x *= scale; a.y *= scale; a.z *= scale; a.w *= scale;
        if (lane < WW / 4)
            *(float4*)(ob + y * WW + 4 * lane) = a;
    }
}

extern "C" void kernel_launch(void* const* d_in, const int* in_sizes, int n_in,
                              void* d_out, int out_size, void* d_ws, size_t ws_size,
                              hipStream_t stream) {
    const float* x_t = (const float*)d_in[0];
    float* out = (float*)d_out;
    const int B = in_sizes[0] / (NT * 2);   // 512
    heatmap_kernel<<<B, BLK, 0, stream>>>(x_t, out);
}

// Round 5
// 113.471 us; speedup vs baseline: 3.9313x; 1.6145x over previous
//
#include <hip/hip_runtime.h>

// Gaussian-splat heatmap via separable gather, register-tiled.
//   x_t [B=512, T=64, 2] f32 -> heat [B, 200, 200] f32, per-image max-normalized.
// heat[y][x] = sum_p R_p(y) * C_p(x), R_p(y)=k1n[y-ys_p] masked to [0,ky_p),
// C_p(x)=k1n[x-xs_p] masked to [0,kx_p)  (reference's top-left-slice quirk).
// One block per image, 4 waves x 50 rows. Each lane: 8-row x 4-col register tile
// (32 independent FMA chains). Active points per 8-row chunk found once via
// __ballot -> wave-uniform mask loop (no divergence). Cmat[64][200] f32 in LDS;
// R from a zero-padded k1n (broadcast reads + ky-clip cndmask). Two passes:
// max, then recompute + normalized store. LDS ~54 KB -> up to 3 blocks/CU.

#define HH 200
#define WW 200
#define HALF 18          // kernel half-size (SIZE=36)
#define KSZ 37
#define NT 64            // points per image
#define BLK 256
#define RPW 50           // rows per wave
#define CH 8             // rows per chunk (register tile height)
#define PADOFF 164
#define PADSZ 372        // zero-padded k1n: [PADOFF, PADOFF+36] = k1n, rest 0

struct SMem {
    float Cmat[NT][WW];           // 51,200 B
    float k1npad[PADSZ];          // 1,488 B
    int xs[NT], ys[NT], kx[NT], ky[NT];
    float wmax[4];
};

// Compute the 8x4 tile for rows [y0, y0+CH) at cols [xb, xb+4). All 64 lanes
// must call (contains __ballot). acc rows beyond the wave's band are garbage-free
// zeros-from-pad and are simply ignored by callers.
static __device__ inline void chunk_acc(const SMem& s, int myys, int myky,
                                        int y0, int xb, float4* acc) {
    #pragma unroll
    for (int i = 0; i < CH; ++i) acc[i] = float4{0.0f, 0.0f, 0.0f, 0.0f};
    unsigned long long mask = __ballot((myys <= y0 + CH - 1) && (myys + myky > y0));
    while (mask) {
        int p = (int)__builtin_ctzll(mask);
        mask &= mask - 1;
        int d = y0 - s.ys[p];            // in [-7, 35] given the ballot condition
        int kyp = s.ky[p];
        const float4 C = *(const float4*)&s.Cmat[p][xb];
        float R[CH];
        #pragma unroll
        for (int i = 0; i < CH; ++i) {
            float rv = s.k1npad[PADOFF + d + i];       // 0 outside [0,36]
            R[i] = (d + i < kyp) ? rv : 0.0f;          // top-left slice: rows >= ky cut
        }
        #pragma unroll
        for (int i = 0; i < CH; ++i) {
            acc[i].x = fmaf(R[i], C.x, acc[i].x);
            acc[i].y = fmaf(R[i], C.y, acc[i].y);
            acc[i].z = fmaf(R[i], C.z, acc[i].z);
            acc[i].w = fmaf(R[i], C.w, acc[i].w);
        }
    }
}

__global__ __launch_bounds__(BLK) void heatmap_kernel(const float* __restrict__ x_t,
                                                      float* __restrict__ out) {
    __shared__ SMem s;
    const int tid  = threadIdx.x;
    const int lane = tid & 63;
    const int wv   = tid >> 6;
    const int b    = blockIdx.x;

    // --- init: zero k1npad; per-point meta (replicates reference exactly) ---
    for (int i = tid; i < PADSZ; i += BLK) s.k1npad[i] = 0.0f;
    if (tid < NT) {
        float x = x_t[((size_t)b * NT + tid) * 2 + 0];
        float y = x_t[((size_t)b * NT + tid) * 2 + 1];
        bool valid = (x == x) && (y == y);                // !isnan
        int xp = (int)(x * 2.0f);                         // trunc == astype(int32), x>=0
        int yp = HH - (int)(y * 2.0f);
        int xs_ = min(max(xp - HALF, 0), WW - 2 * HALF);  // clip(.., 0, 164)
        int ys_ = min(max(yp - HALF, 0), HH - 2 * HALF);
        int xe  = min(max(xp + HALF, 0), WW);
        int ye  = min(max(yp + HALF, 0), HH);
        s.xs[tid] = xs_;
        s.ys[tid] = ys_;
        s.kx[tid] = valid ? (xe - xs_) : 0;               // <= 36 always
        s.ky[tid] = valid ? (ye - ys_) : 0;
    }
    __syncthreads();

    // --- normalized 1-D kernel into the pad's center ---
    if (tid < KSZ) {
        float sum = 0.0f, mine = 0.0f;
        #pragma unroll
        for (int i = 0; i < KSZ; ++i) {
            float r = (float)(i - HALF);
            float v = expf(-(r * r) * (1.0f / 18.0f));    // sigma=3 -> 2*sigma^2=18
            sum += v;
            if (i == tid) mine = v;
        }
        s.k1npad[PADOFF + tid] = mine / sum;
    }
    __syncthreads();

    // --- build Cmat: 4 threads per point, 50 consecutive cols each ---
    {
        int p   = tid >> 2;
        int xs_ = s.xs[p];
        unsigned kx_ = (unsigned)s.kx[p];
        int x0  = (tid & 3) * 50;
        #pragma unroll 10
        for (int k = 0; k < 50; ++k) {
            int x = x0 + k;
            unsigned c = (unsigned)(x - xs_);
            s.Cmat[p][x] = (c < kx_) ? s.k1npad[PADOFF + (int)c] : 0.0f;
        }
    }
    __syncthreads();

    const int xb    = min(lane * 4, WW - 4);   // lanes >= 50 duplicate cols 196..199
    const int ybase = wv * RPW;
    const int myys  = s.ys[lane];
    const int myky  = s.ky[lane];

    // --- pass 1: max ---
    float gmax = 0.0f;
    for (int c = 0; c < (RPW + CH - 1) / CH; ++c) {
        const int y0 = ybase + c * CH;
        float4 acc[CH];
        chunk_acc(s, myys, myky, y0, xb, acc);
        const int nv = min(CH, RPW - c * CH);
        for (int i = 0; i < nv; ++i)
            gmax = fmaxf(gmax, fmaxf(fmaxf(acc[i].x, acc[i].y), fmaxf(acc[i].z, acc[i].w)));
    }
    #pragma unroll
    for (int off = 32; off > 0; off >>= 1) gmax = fmaxf(gmax, __shfl_xor(gmax, off));
    if (lane == 0) s.wmax[wv] = gmax;
    __syncthreads();
    const float mm = fmaxf(fmaxf(s.wmax[0], s.wmax[1]), fmaxf(s.wmax[2], s.wmax[3]));
    const float scale = 1.0f / (mm + 1e-10f);

    // --- pass 2: recompute, normalize, coalesced float4 store ---
    float* ob = out + (size_t)b * (HH * WW);
    for (int c = 0; c < (RPW + CH - 1) / CH; ++c) {
        const int y0 = ybase + c * CH;
        float4 acc[CH];
        chunk_acc(s, myys, myky, y0, xb, acc);
        const int nv = min(CH, RPW - c * CH);
        if (lane < WW / 4) {
            for (int i = 0; i < nv; ++i) {
                float4 v = acc[i];
                v.x *= scale; v.y *= scale; v.z *= scale; v.w *= scale;
                *(float4*)(ob + (size_t)(y0 + i) * WW + lane * 4) = v;
            }
        }
    }
}

extern "C" void kernel_launch(void* const* d_in, const int* in_sizes, int n_in,
                              void* d_out, int out_size, void* d_ws, size_t ws_size,
                              hipStream_t stream) {
    const float* x_t = (const float*)d_in[0];
    float* out = (float*)d_out;
    const int B = in_sizes[0] / (NT * 2);   // 512
    heatmap_kernel<<<B, BLK, 0, stream>>>(x_t, out);
}

// Round 6
// 24.902 us; speedup vs baseline: 17.9136x; 4.5566x over previous
//
#include <hip/hip_runtime.h>

// Gaussian-splat heatmap as a per-image MFMA GEMM.
//   heat[y][x] = sum_p Rmat[y][p] * CmatT[x][p]   (M=200, N=200, K=64 points)
// Rmat[y][p]  = k1n[y-ys_p] if 0<=y-ys_p<ky_p else 0   (top-left-slice quirk)
// CmatT[x][p] = k1n[x-xs_p] if 0<=x-xs_p<kx_p else 0
// Both stored bf16 in LDS as [224][64] (rows padded to 224 = 7*32; pad rows are
// automatically zero since ys,xs<=164, ky,kx<=36). Row = 128 B -> XOR-swizzle
// byte ^= ((row&7)<<4) so ds_read_b128 fragment reads are conflict-light (G4/T2).
// mfma_f32_32x32x16_bf16, 7x7 tiles, 4 MFMA per tile (K=64).
//   A-frag: lane l -> row = l&31, k = 8*(l>>5)+j (k-contig -> one b128 per MFMA)
//   C/D  : col = lane&31, row = (reg&3)+8*(reg>>2)+4*(lane>>5)   [verified m74/m101]
// 512 threads = 8 waves; wave w owns tile-row w (A-frags loaded once, reused over
// 7 B-tiles); wave 7 idles in compute. Pass 1: block max from accumulators.
// Pass 2: recompute + scaled stores (lanes 0-31 write 128 B contiguous).
// LDS ~57 KB -> 2 blocks/CU; grid 512 = 2 blocks/CU exactly.

#define NT 64
#define BLK 512
#define TDIM 224
#define NTL 7            // 7 tiles of 32 per dim

typedef short bf16x8 __attribute__((ext_vector_type(8)));
typedef float f32x16 __attribute__((ext_vector_type(16)));

// f32 -> bf16 round-to-nearest-even
static __device__ inline unsigned short f2bf(float f) {
    unsigned int u = __float_as_uint(f);
    u = (u + 0x7FFFu + ((u >> 16) & 1u)) >> 16;
    return (unsigned short)u;
}

struct __align__(16) SMem {
    unsigned short Rm[TDIM][64];   // 28,672 B, swizzled
    unsigned short Cm[TDIM][64];   // 28,672 B, swizzled
    unsigned short k1b[40];        // bf16 normalized 1-D gaussian
    float wmax[8];
};

__global__ __launch_bounds__(BLK, 4) void heatmap_kernel(const float* __restrict__ x_t,
                                                         float* __restrict__ out) {
    __shared__ SMem s;
    const int tid  = threadIdx.x;
    const int lane = tid & 63;
    const int wv   = tid >> 6;
    const int b    = blockIdx.x;

    // --- normalized 1-D gaussian table, bf16 ---
    if (tid < 37) {
        float sum = 0.0f, mine = 0.0f;
        #pragma unroll
        for (int i = 0; i < 37; ++i) {
            float r = (float)(i - 18);
            float v = expf(-(r * r) * (1.0f / 18.0f));   // sigma=3 -> 2*sigma^2=18
            sum += v;
            if (i == tid) mine = v;
        }
        s.k1b[tid] = f2bf(mine / sum);
    }
    __syncthreads();

    // --- build Rm (rows=y) and Cm (rows=x); each thread owns point-pair q ---
    {
        const int q  = tid & 31;    // points 2q, 2q+1
        const int r0 = tid >> 5;    // 0..15, row stride 16
        float4 pxy = *(const float4*)(x_t + (size_t)b * NT * 2 + 4 * q);
        // point 2q  (replicates reference exactly)
        bool v0 = (pxy.x == pxy.x) && (pxy.y == pxy.y);
        int xp0 = (int)(pxy.x * 2.0f), yp0 = 200 - (int)(pxy.y * 2.0f);
        int xs0 = min(max(xp0 - 18, 0), 164), ys0 = min(max(yp0 - 18, 0), 164);
        int kx0 = v0 ? (min(max(xp0 + 18, 0), 200) - xs0) : 0;
        int ky0 = v0 ? (min(max(yp0 + 18, 0), 200) - ys0) : 0;
        // point 2q+1
        bool v1 = (pxy.z == pxy.z) && (pxy.w == pxy.w);
        int xp1 = (int)(pxy.z * 2.0f), yp1 = 200 - (int)(pxy.w * 2.0f);
        int xs1 = min(max(xp1 - 18, 0), 164), ys1 = min(max(yp1 - 18, 0), 164);
        int kx1 = v1 ? (min(max(xp1 + 18, 0), 200) - xs1) : 0;
        int ky1 = v1 ? (min(max(yp1 + 18, 0), 200) - ys1) : 0;

        for (int i = 0; i < TDIM / 16; ++i) {
            int row = r0 + 16 * i;
            int sw  = (4 * q) ^ ((row & 7) << 4);
            // Rm: k index = point
            int d0 = row - ys0, d1 = row - ys1;
            unsigned a0 = ((unsigned)d0 < (unsigned)ky0) ? s.k1b[d0] : 0u;
            unsigned a1 = ((unsigned)d1 < (unsigned)ky1) ? s.k1b[d1] : 0u;
            *(unsigned*)((char*)s.Rm + row * 128 + sw) = a0 | (a1 << 16);
            // Cm
            int e0 = row - xs0, e1 = row - xs1;
            unsigned c0 = ((unsigned)e0 < (unsigned)kx0) ? s.k1b[e0] : 0u;
            unsigned c1 = ((unsigned)e1 < (unsigned)kx1) ? s.k1b[e1] : 0u;
            *(unsigned*)((char*)s.Cm + row * 128 + sw) = c0 | (c1 << 16);
        }
    }
    __syncthreads();

    const int ty  = wv;                 // waves 0..6 compute tile-row ty; wave 7 idle
    const int swl = (lane & 7) << 4;    // swizzle term (row&7 == lane&7, rows = t*32+(lane&31))
    bf16x8 A[4];
    if (ty < NTL) {
        const char* ab = (const char*)s.Rm + (ty * 32 + (lane & 31)) * 128;
        #pragma unroll
        for (int m = 0; m < 4; ++m)
            A[m] = *(const bf16x8*)(ab + ((16 * (2 * m + (lane >> 5))) ^ swl));
    }

    // ---- pass 1: max over all tiles ----
    float gmax = 0.0f;
    if (ty < NTL) {
        for (int tx = 0; tx < NTL; ++tx) {
            const char* bb = (const char*)s.Cm + (tx * 32 + (lane & 31)) * 128;
            f32x16 acc;
            #pragma unroll
            for (int r = 0; r < 16; ++r) acc[r] = 0.0f;
            #pragma unroll
            for (int m = 0; m < 4; ++m) {
                bf16x8 B = *(const bf16x8*)(bb + ((16 * (2 * m + (lane >> 5))) ^ swl));
                acc = __builtin_amdgcn_mfma_f32_32x32x16_bf16(A[m], B, acc, 0, 0, 0);
            }
            #pragma unroll
            for (int r = 0; r < 16; ++r) gmax = fmaxf(gmax, acc[r]);
        }
    }
    #pragma unroll
    for (int off = 32; off > 0; off >>= 1) gmax = fmaxf(gmax, __shfl_xor(gmax, off));
    if (lane == 0) s.wmax[wv] = gmax;
    __syncthreads();
    float mm = s.wmax[0];
    #pragma unroll
    for (int w = 1; w < 8; ++w) mm = fmaxf(mm, s.wmax[w]);
    const float scale = 1.0f / (mm + 1e-10f);

    // ---- pass 2: recompute, normalize, store ----
    if (ty < NTL) {
        float* ob = out + (size_t)b * (200 * 200);
        for (int tx = 0; tx < NTL; ++tx) {
            const char* bb = (const char*)s.Cm + (tx * 32 + (lane & 31)) * 128;
            f32x16 acc;
            #pragma unroll
            for (int r = 0; r < 16; ++r) acc[r] = 0.0f;
            #pragma unroll
            for (int m = 0; m < 4; ++m) {
                bf16x8 B = *(const bf16x8*)(bb + ((16 * (2 * m + (lane >> 5))) ^ swl));
                acc = __builtin_amdgcn_mfma_f32_32x32x16_bf16(A[m], B, acc, 0, 0, 0);
            }
            const int gcol = tx * 32 + (lane & 31);
            #pragma unroll
            for (int r = 0; r < 16; ++r) {
                int grow = ty * 32 + (r & 3) + 8 * (r >> 2) + 4 * (lane >> 5);
                if (grow < 200 && gcol < 200)
                    ob[grow * 200 + gcol] = acc[r] * scale;
            }
        }
    }
}

extern "C" void kernel_launch(void* const* d_in, const int* in_sizes, int n_in,
                              void* d_out, int out_size, void* d_ws, size_t ws_size,
                              hipStream_t stream) {
    const float* x_t = (const float*)d_in[0];
    float* out = (float*)d_out;
    const int B = in_sizes[0] / (NT * 2);   // 512
    heatmap_kernel<<<B, BLK, 0, stream>>>(x_t, out);
}